// Round 1
// baseline (25.689 us; speedup 1.0000x reference)
//
#include <hip/hip_runtime.h>
#include <cfloat>
#include <math.h>

// TripletCenterLoss, collapsed from O(B^2) to O(B*C):
//   dist_ap[i] = ||x_i - centers[t_i]||            (all same-class j share it; j=i exists)
//   dist_an[i] = min_{c present in targets, c != t_i} ||x_i - centers[c]||
//   loss = mean(relu(MARGIN + dist_ap - dist_an))
// with dist = sqrt(max(d2, 1e-12)) matching jnp.sqrt(jnp.clip(d2, 1e-12)).

constexpr int D = 128;             // feature dim
constexpr int C = 100;             // num classes
constexpr int NPART = 8;           // lanes per row (class partitions)
constexpr int CPART = 13;          // ceil(C / NPART); 8*13 = 104 (guard cc < C)
constexpr int CROWS = NPART * CPART;  // 104 padded center rows in LDS
constexpr int ROWS_PER_BLOCK = 32; // 256 threads / 8 parts
constexpr int D4 = D / 4;          // 32 float4 chunks
constexpr int LDS_STRIDE = 132;    // floats; 13*132 % 32 = 20 -> 8 parts hit disjoint banks
constexpr float MARGIN = 5.0f;

__global__ __launch_bounds__(256) void tcl_main(
    const float* __restrict__ x, const int* __restrict__ tgt,
    const float* __restrict__ cen, float* __restrict__ partial, int B)
{
    __shared__ float ldsC[CROWS * LDS_STRIDE];
    __shared__ unsigned char present[CROWS];
    __shared__ float wred[4];

    const int tid = threadIdx.x;

    // --- stage centers into LDS (zero-fill the 4 padding rows) ---
    for (int i = tid; i < CROWS * D4; i += 256) {
        const int c  = i >> 5;        // / D4
        const int d4 = i & (D4 - 1);  // % D4
        float4 v = make_float4(0.f, 0.f, 0.f, 0.f);
        if (c < C) v = reinterpret_cast<const float4*>(cen)[c * D4 + d4];
        *reinterpret_cast<float4*>(&ldsC[c * LDS_STRIDE + d4 * 4]) = v;
    }
    for (int i = tid; i < CROWS; i += 256) present[i] = 0;
    __syncthreads();
    // --- class presence bitmap (targets are L2-hot after block 0) ---
    for (int j = tid; j < B; j += 256) present[tgt[j]] = 1;
    __syncthreads();

    const int part = tid & (NPART - 1);
    const int row  = blockIdx.x * ROWS_PER_BLOCK + (tid >> 3);
    const int t    = tgt[row];
    const int c0   = part * CPART;
    const float4* __restrict__ xrow =
        reinterpret_cast<const float4*>(x + (size_t)row * D);

    float acc[CPART];
    #pragma unroll
    for (int c = 0; c < CPART; ++c) acc[c] = 0.0f;

    #pragma unroll 4
    for (int d4 = 0; d4 < D4; ++d4) {
        const float4 xv = xrow[d4];
        #pragma unroll
        for (int c = 0; c < CPART; ++c) {
            const float4 cv = *reinterpret_cast<const float4*>(
                &ldsC[(c0 + c) * LDS_STRIDE + d4 * 4]);
            const float dx = xv.x - cv.x;
            const float dy = xv.y - cv.y;
            const float dz = xv.z - cv.z;
            const float dw = xv.w - cv.w;
            acc[c] += dx * dx + dy * dy + dz * dz + dw * dw;
        }
    }

    // --- per-part ap^2 / an^2 ---
    float ap2 = -FLT_MAX;
    float an2 = FLT_MAX;
    #pragma unroll
    for (int c = 0; c < CPART; ++c) {
        const int cc = c0 + c;
        if (cc < C) {
            const bool own = (cc == t);
            if (own) ap2 = acc[c];
            if (!own && present[cc]) an2 = fminf(an2, acc[c]);
        }
    }
    // --- combine across the 8 lanes of this row ---
    #pragma unroll
    for (int off = 1; off < NPART; off <<= 1) {
        ap2 = fmaxf(ap2, __shfl_xor(ap2, off));
        an2 = fminf(an2, __shfl_xor(an2, off));
    }

    float term = 0.0f;
    if (part == 0) {
        const float ap = sqrtf(fmaxf(ap2, 1e-12f));
        if (an2 < FLT_MAX) {  // some other class present (always true here)
            const float an = sqrtf(fmaxf(an2, 1e-12f));
            term = fmaxf(0.0f, MARGIN + ap - an);
        } else {
            term = 0.0f;      // an = +inf -> relu(-inf) = 0
        }
    }
    // --- deterministic block sum: wave shuffle-reduce then LDS combine ---
    #pragma unroll
    for (int off = 1; off < 64; off <<= 1) term += __shfl_xor(term, off);
    if ((tid & 63) == 0) wred[tid >> 6] = term;
    __syncthreads();
    if (tid == 0)
        partial[blockIdx.x] = (wred[0] + wred[1]) + (wred[2] + wred[3]);
}

__global__ __launch_bounds__(256) void tcl_reduce(
    const float* __restrict__ partial, float* __restrict__ out,
    int n, float invB)
{
    __shared__ float wred[4];
    const int tid = threadIdx.x;
    float v = (tid < n) ? partial[tid] : 0.0f;
    #pragma unroll
    for (int off = 1; off < 64; off <<= 1) v += __shfl_xor(v, off);
    if ((tid & 63) == 0) wred[tid >> 6] = v;
    __syncthreads();
    if (tid == 0)
        out[0] = ((wred[0] + wred[1]) + (wred[2] + wred[3])) * invB;
}

extern "C" void kernel_launch(void* const* d_in, const int* in_sizes, int n_in,
                              void* d_out, int out_size, void* d_ws, size_t ws_size,
                              hipStream_t stream)
{
    const float* x   = (const float*)d_in[0];   // [B, D] f32
    const int*   tgt = (const int*)d_in[1];     // [B] int
    const float* cen = (const float*)d_in[2];   // [C, D] f32
    float* out = (float*)d_out;                 // scalar f32
    float* partial = (float*)d_ws;

    const int B = in_sizes[1];                  // 8192
    const int nblocks = B / ROWS_PER_BLOCK;     // 256

    tcl_main<<<nblocks, 256, 0, stream>>>(x, tgt, cen, partial, B);
    tcl_reduce<<<1, 256, 0, stream>>>(partial, out, nblocks, 1.0f / (float)B);
}

// Round 2
// 18.500 us; speedup vs baseline: 1.3886x; 1.3886x over previous
//
#include <hip/hip_runtime.h>
#include <cfloat>
#include <math.h>

// TripletCenterLoss, collapsed O(B^2) -> O(B*C):
//   dist_ap[i] = ||x_i - centers[t_i]||    (all same-class j share it; j=i exists)
//   dist_an[i] = min_{c present, c != t_i} ||x_i - centers[c]||
//   loss = mean(relu(MARGIN + dist_ap - dist_an))
// d2 via the reference's GEMM expansion: x2 + c2 - 2*x.c, dist = sqrt(clip(d2,1e-12)).
//
// Layout: 256 blocks x 256 threads; each row handled by P=16 lanes; each lane
// owns CPART=7 classes and R=2 rows (center LDS read amortized over 2 rows).
// Centers in LDS with XOR swizzle: chunk d4 of class cl at cl*128 + (d4^(cl&7))*4
// -> the 16 lanes' reads per (c,d4) spread over 8 disjoint 4-bank groups (2-way = free).

constexpr int D = 128;
constexpr int D4 = 32;            // float4 chunks per row
constexpr int C = 100;
constexpr int CPAD = 112;         // 16 parts * 7 classes
constexpr int P = 16;             // lanes per row (class partitions)
constexpr int CPART = 7;          // classes per part
constexpr int R = 2;              // rows per thread
constexpr int T = 256;
constexpr int ROWS_PER_BLOCK = (T / P) * R;  // 32
constexpr float MARGIN = 5.0f;

__device__ __forceinline__ int swz(int cl, int d4) {
    return cl * D + ((d4 ^ (cl & 7)) << 2);   // float offset into ldsC
}
__device__ __forceinline__ float4 fma4(float4 a, float4 b, float4 c) {
    return make_float4(fmaf(a.x, b.x, c.x), fmaf(a.y, b.y, c.y),
                       fmaf(a.z, b.z, c.z), fmaf(a.w, b.w, c.w));
}
__device__ __forceinline__ float hsum4(float4 v) {
    return (v.x + v.y) + (v.z + v.w);
}

__global__ __launch_bounds__(256) void tcl_main(
    const float* __restrict__ x, const int* __restrict__ tgt,
    const float* __restrict__ cen, float* __restrict__ partial, int B)
{
    __shared__ float ldsC[CPAD * D];
    __shared__ float c2s[CPAD];
    __shared__ unsigned char present[CPAD];
    __shared__ float wred[4];
    const int tid = threadIdx.x;

    // --- phase 1: stage centers swizzled (zero-pad cl>=100), clear present ---
    for (int i = tid; i < CPAD * D4; i += T) {
        const int cl = i >> 5, d4 = i & 31;
        float4 v = make_float4(0.f, 0.f, 0.f, 0.f);
        if (cl < C) v = reinterpret_cast<const float4*>(cen)[cl * D4 + d4];
        *reinterpret_cast<float4*>(&ldsC[swz(cl, d4)]) = v;
    }
    for (int i = tid; i < CPAD; i += T) present[i] = 0;
    __syncthreads();

    // --- phase 2: presence bitmap (int4-vectorized) + c2 from global (L2-hot) ---
    for (int i = tid; i < (8192 / 4); i += T) {
        const int4 tv = reinterpret_cast<const int4*>(tgt)[i];
        present[tv.x] = 1; present[tv.y] = 1;
        present[tv.z] = 1; present[tv.w] = 1;
    }
    if (tid < CPAD) {
        float s = 0.f;
        if (tid < C) {
            const float4* cr = reinterpret_cast<const float4*>(cen + tid * D);
            #pragma unroll 8
            for (int d4 = 0; d4 < D4; ++d4) {
                const float4 v = cr[d4];
                s += (v.x * v.x + v.y * v.y) + (v.z * v.z + v.w * v.w);
            }
        }
        c2s[tid] = s;
    }
    __syncthreads();

    // --- main: R=2 rows per thread, CPART=7 classes, dot-products ---
    const int p    = tid & (P - 1);
    const int g    = tid >> 4;                       // rowgroup 0..15
    const int row0 = blockIdx.x * ROWS_PER_BLOCK + g * R;
    const int t0 = tgt[row0], t1 = tgt[row0 + 1];
    const float4* __restrict__ xr0 = reinterpret_cast<const float4*>(x + (size_t)row0 * D);
    const float4* __restrict__ xr1 = reinterpret_cast<const float4*>(x + (size_t)(row0 + 1) * D);
    const int cl0 = p * CPART;

    float4 a0[CPART], a1[CPART];
    float4 x2v0 = make_float4(0.f, 0.f, 0.f, 0.f);
    float4 x2v1 = make_float4(0.f, 0.f, 0.f, 0.f);
    #pragma unroll
    for (int c = 0; c < CPART; ++c) {
        a0[c] = make_float4(0.f, 0.f, 0.f, 0.f);
        a1[c] = make_float4(0.f, 0.f, 0.f, 0.f);
    }

    #pragma unroll 4
    for (int d4 = 0; d4 < D4; ++d4) {
        const float4 xv0 = xr0[d4];
        const float4 xv1 = xr1[d4];
        x2v0 = fma4(xv0, xv0, x2v0);
        x2v1 = fma4(xv1, xv1, x2v1);
        #pragma unroll
        for (int c = 0; c < CPART; ++c) {
            const float4 cv = *reinterpret_cast<const float4*>(&ldsC[swz(cl0 + c, d4)]);
            a0[c] = fma4(xv0, cv, a0[c]);
            a1[c] = fma4(xv1, cv, a1[c]);
        }
    }

    // --- epilogue: d2 = x2 + c2 - 2*dot; per-part ap2/an2 then 16-lane reduce ---
    const float x20 = hsum4(x2v0);
    const float x21 = hsum4(x2v1);
    float ap0 = -INFINITY, ap1 = -INFINITY;
    float an0 =  INFINITY, an1 =  INFINITY;
    #pragma unroll
    for (int c = 0; c < CPART; ++c) {
        const int cl = cl0 + c;
        if (cl < C) {
            const float d20 = x20 + c2s[cl] - 2.f * hsum4(a0[c]);
            const float d21 = x21 + c2s[cl] - 2.f * hsum4(a1[c]);
            const bool pr = present[cl] != 0;
            if (cl == t0)      ap0 = d20;
            else if (pr)       an0 = fminf(an0, d20);
            if (cl == t1)      ap1 = d21;
            else if (pr)       an1 = fminf(an1, d21);
        }
    }
    #pragma unroll
    for (int off = 1; off < P; off <<= 1) {
        ap0 = fmaxf(ap0, __shfl_xor(ap0, off));
        ap1 = fmaxf(ap1, __shfl_xor(ap1, off));
        an0 = fminf(an0, __shfl_xor(an0, off));
        an1 = fminf(an1, __shfl_xor(an1, off));
    }

    float term = 0.f;
    if (p == 0) {
        const float apd0 = sqrtf(fmaxf(ap0, 1e-12f));
        const float and0 = sqrtf(fmaxf(an0, 1e-12f));   // INF if no other class (never here)
        const float apd1 = sqrtf(fmaxf(ap1, 1e-12f));
        const float and1 = sqrtf(fmaxf(an1, 1e-12f));
        term = fmaxf(0.f, MARGIN + apd0 - and0) + fmaxf(0.f, MARGIN + apd1 - and1);
    }
    // block sum (bitwise-deterministic): combine the 4 part-0 lanes of each wave
    term += __shfl_xor(term, 16);
    term += __shfl_xor(term, 32);
    if ((tid & 63) == 0) wred[tid >> 6] = term;
    __syncthreads();
    if (tid == 0) partial[blockIdx.x] = (wred[0] + wred[1]) + (wred[2] + wred[3]);
}

__global__ __launch_bounds__(256) void tcl_reduce(
    const float* __restrict__ partial, float* __restrict__ out,
    int n, float invB)
{
    __shared__ float wred[4];
    const int tid = threadIdx.x;
    float v = (tid < n) ? partial[tid] : 0.0f;
    #pragma unroll
    for (int off = 1; off < 64; off <<= 1) v += __shfl_xor(v, off);
    if ((tid & 63) == 0) wred[tid >> 6] = v;
    __syncthreads();
    if (tid == 0)
        out[0] = ((wred[0] + wred[1]) + (wred[2] + wred[3])) * invB;
}

extern "C" void kernel_launch(void* const* d_in, const int* in_sizes, int n_in,
                              void* d_out, int out_size, void* d_ws, size_t ws_size,
                              hipStream_t stream)
{
    const float* x   = (const float*)d_in[0];   // [B, D] f32
    const int*   tgt = (const int*)d_in[1];     // [B] int32 (harness-converted)
    const float* cen = (const float*)d_in[2];   // [C, D] f32
    float* out = (float*)d_out;                 // scalar f32
    float* partial = (float*)d_ws;

    const int B = in_sizes[1];                  // 8192
    const int nblocks = B / ROWS_PER_BLOCK;     // 256

    tcl_main<<<nblocks, T, 0, stream>>>(x, tgt, cen, partial, B);
    tcl_reduce<<<1, 256, 0, stream>>>(partial, out, nblocks, 1.0f / (float)B);
}